// Round 8
// baseline (412.494 us; speedup 1.0000x reference)
//
#include <hip/hip_runtime.h>
#include <stdint.h>

using f16 = _Float16;

typedef _Float16 f16x8 __attribute__((ext_vector_type(8)));
typedef _Float16 f16x4 __attribute__((ext_vector_type(4)));
typedef float f32x4 __attribute__((ext_vector_type(4)));

#define LOG2E 1.44269504088896340736f

__device__ __forceinline__ f16 f2h(float f) { return (f16)f; }  // RNE

#if __has_builtin(__builtin_amdgcn_exp2f)
__device__ __forceinline__ float fexp2(float x) { return __builtin_amdgcn_exp2f(x); }
#else
__device__ __forceinline__ float fexp2(float x) { return exp2f(x); }
#endif

typedef __attribute__((address_space(1))) const uint32_t gu32;
typedef __attribute__((address_space(3))) uint32_t lu32;

__device__ __forceinline__ void dma16(const void* g, void* l) {
  // global->LDS DMA, 16 B/lane. Global source is PER-LANE (caller includes
  // lane*16B); LDS dest is wave-uniform base + lane*16 auto-stride.
  __builtin_amdgcn_global_load_lds((gu32*)g, (lu32*)l, 16, 0, 0);
}

__device__ __forceinline__ f16x8 cvt8(const float* p) {
  const float4 a = *(const float4*)p;
  const float4 b = *(const float4*)(p + 4);
  f16x8 r;
  r[0] = (f16)a.x; r[1] = (f16)a.y; r[2] = (f16)a.z; r[3] = (f16)a.w;
  r[4] = (f16)b.x; r[5] = (f16)b.y; r[6] = (f16)b.z; r[7] = (f16)b.w;
  return r;
}

// B=4, C=64, N=4096.  Global in/out FP32; internal tensor-core path FP16.
// ws layout (bytes):
//   0     qa  f16 [4][4096][64]      (2 MB)  q*log2e, position-major
//   2 MB  ka2 f16 [4][8][4096][8]    (2 MB)  K: [b][c8][key'][8c], key' = key
//                                            ^ ((key>>3&1)<<2 | (key>>4&1))
//   4 MB  va3 f16 [4][512][64][8]    (2 MB)  V key-chunked: [b][k8][c][8k]
//   6 MB  gs1[64] | gs2[64] | ctr[2] (BN stats + grid-barrier counters)
// (y0 is GONE: BN+residual applied straight from LDS in phase C.)

// ---------------------------------------------------------------------------
// zeroer: BN stats + barrier counters (ws is garbage at entry; graph replays
// re-run this each iteration, resetting the monotonic counters).
// ---------------------------------------------------------------------------
__global__ __launch_bounds__(256, 1) void pam_zero(float* gz, int* ctr) {
  if (threadIdx.x < 128) gz[threadIdx.x] = 0.f;
  if (threadIdx.x < 2) ctr[threadIdx.x] = 0;
}

// ---------------------------------------------------------------------------
// fused: pre -> gridbar -> attn -> gridbar -> BN+residual, ONE launch.
//  - grid 512 x 512 thr.  Per-block resources (~42 KB LDS, ~60 VGPR) give
//    >=2 blocks/CU capacity -> all 512 blocks co-resident -> spin-barrier is
//    deadlock-free.  Barriers: __threadfence (device-scope release; covers
//    cross-XCD L2 per Guideline 16) + atomicAdd ticket + acquire spin +
//    __threadfence (invalidate) in all waves.
//  - Phase A: block (b = blk&3, qb0 = (blk>>2)*32) computes pre for ITS OWN
//    32 positions (x-stage -> conv q/k -> V-proj MFMA).  Its attn Q-slice is
//    then L1/L2-hot.
//  - Phase B: r7 attn verbatim (K 128-key DMA double-buffer, V global->VGPR,
//    XOR K-perm gather -> zero-shuffle P, O^T PV, defer-max), minus y0 store.
//  - Phase C: BN scale/shift from gs1/gs2 + residual, sourced from ldsO
//    STILL IN LDS (no y0 global round-trip).
// ---------------------------------------------------------------------------
__global__ __launch_bounds__(512, 2) void pam_fused(
    const float* __restrict__ x, const float* __restrict__ qw,
    const float* __restrict__ kw, const float* __restrict__ vw,
    const float* __restrict__ vb, const float* __restrict__ gam,
    const float* __restrict__ bnw, const float* __restrict__ bnb,
    f16* __restrict__ qa, f16* __restrict__ ka2, f16* __restrict__ va3,
    float* __restrict__ gs1, float* __restrict__ gs2, int* __restrict__ ctr,
    float* __restrict__ out)
{
  __shared__ alignas(16) f16 kbuf[2][8192];   // 32 KB; phase A reuses [0] as xt
  __shared__ float ldsO[32 * 65];             // [q][c], pad 65
  __shared__ float ldsM[4][32], ldsL[4][32], ldsMg[32], ldsInv[32];

  const int tid = threadIdx.x;
  const int wv = tid >> 6, lane = tid & 63;
  const int quad = lane >> 4, l15 = lane & 15;
  const int ks = wv & 3, qh = wv >> 2;
  const int b = blockIdx.x & 3;
  const int qb = blockIdx.x >> 2;          // 0..127
  const int qb0 = qb << 5;
  const int phase = qb & 31;               // anti-convoy rotation (32 tiles)

  for (int i = tid; i < 32 * 65; i += 512) ldsO[i] = 0.f;

  // ===== Phase A: pre for this block's 32 positions =====
  f16* const xt = kbuf[0];                 // [32][72] f16
  {
    const int c = tid >> 3;
    const int j0 = (tid & 7) << 2;
    const float4 v0 = *(const float4*)(x + ((size_t)(b * 64 + c) << 12) + qb0 + j0);
    xt[(j0 + 0) * 72 + c] = f2h(v0.x);
    xt[(j0 + 1) * 72 + c] = f2h(v0.y);
    xt[(j0 + 2) * 72 + c] = f2h(v0.z);
    xt[(j0 + 3) * 72 + c] = f2h(v0.w);
  }
  __syncthreads();

  if (tid < 256) {      // conv over channel axis (SAME, zero pad)
    const float qw0 = qw[0], qw1 = qw[1], qw2 = qw[2];
    const float kw0 = kw[0], kw1 = kw[1], kw2 = kw[2];
    const int n = tid >> 3;            // 0..31
    const int c8 = tid & 7;            // 0..7
    const f16x8 v0 = *(const f16x8*)&xt[n * 72 + c8 * 8];
    const float lm = (c8 > 0) ? (float)xt[n * 72 + c8 * 8 - 1] : 0.f;
    const float rp = (c8 < 7) ? (float)xt[n * 72 + c8 * 8 + 8] : 0.f;
    f16x8 qv8, kv8;
#pragma unroll
    for (int j = 0; j < 8; ++j) {
      const float xm = (j == 0) ? lm : (float)v0[j - 1];
      const float x0 = (float)v0[j];
      const float xp = (j == 7) ? rp : (float)v0[j + 1];
      qv8[j] = f2h((qw0 * xm + qw1 * x0 + qw2 * xp) * LOG2E);  // log2-domain
      kv8[j] = f2h(kw0 * xm + kw1 * x0 + kw2 * xp);
    }
    const int nn = qb0 + n;
    *(f16x8*)(qa + ((size_t)((b << 12) + nn) << 6) + c8 * 8) = qv8;
    // bank-fix storage permutation (attn gather expects it)
    const int np = nn ^ ((((nn >> 3) & 1) << 2) | ((nn >> 4) & 1));
    *(f16x8*)(ka2 + (((size_t)(b * 8 + c8)) << 15) + (np << 3)) = kv8;
  }

  {   // v^T via mfma; wave wv -> (n-subtile wv&1, co-group wv>>1)
    const int nt = wv & 1, cg = wv >> 1;
    const f16x8 a0 = *(const f16x8*)&xt[(nt * 16 + l15) * 72 + quad * 8];
    const f16x8 a1 = *(const f16x8*)&xt[(nt * 16 + l15) * 72 + quad * 8 + 32];
    const int co = cg * 16 + l15;
    const f16x8 b0 = cvt8(vw + co * 64 + quad * 8);
    const f16x8 b1 = cvt8(vw + co * 64 + quad * 8 + 32);
    f32x4 z = {0.f, 0.f, 0.f, 0.f};
    z = __builtin_amdgcn_mfma_f32_16x16x32_f16(a0, b0, z, 0, 0, 0);
    z = __builtin_amdgcn_mfma_f32_16x16x32_f16(a1, b1, z, 0, 0, 0);
    const float vbv = vb[co];
    f16x4 pv;
#pragma unroll
    for (int r = 0; r < 4; ++r) pv[r] = f2h(z[r] + vbv);
    const int nb = qb0 + nt * 16 + quad * 4;   // 4 consecutive n
    *(f16x4*)(va3 + (((size_t)(b * 512 + (nb >> 3))) << 9)
              + (co << 3) + (nb & 7)) = pv;
  }

  // ===== grid barrier 1: pre outputs visible everywhere =====
  __syncthreads();
  __threadfence();
  if (tid == 0) {
    atomicAdd(ctr, 1);
    while (__hip_atomic_load(ctr, __ATOMIC_RELAXED, __HIP_MEMORY_SCOPE_AGENT) < 512)
      __builtin_amdgcn_s_sleep(8);
  }
  __syncthreads();
  __threadfence();

  // ===== Phase B: attention (r7, minus y0 store) =====
  const int bn = b << 12;
  f16x8 bq0, bq1;
  {
    const int q = qb0 + qh * 16 + l15;
    const f16* qp = qa + ((size_t)(bn + q) << 6) + quad * 8;
    bq0 = *(const f16x8*)qp;
    bq1 = *(const f16x8*)(qp + 32);
  }

  const f16* kg0 = ka2 + (((size_t)(b * 8 + wv)) << 15) + (lane << 3);
  const f16* vgp = va3 + ((size_t)b << 18) + ((ks * 4 + quad) << 9) + (l15 << 3);

  f32x4 o[4] = {};                 // O^T: col=l15=q, row c = ct*16+quad*4+r
  float m = -1e30f, lp = 0.f;

  dma16(kg0 + ((size_t)phase << 10),       kbuf[0] + (wv << 10));
  dma16(kg0 + ((size_t)phase << 10) + 512, kbuf[0] + (wv << 10) + 512);
  __syncthreads();

  const int u = l15 >> 2;
  const int xmsk = ((u & 1) << 2) | (u >> 1);
  const int pos0 = (ks << 5) + (u << 3) + (l15 & 3);
  const int koff0 = (pos0 ^ xmsk) << 3;
  const int koff1 = koff0 ^ 32;

#pragma unroll 1
  for (int kt = 0; kt < 32; ++kt) {
    const int cur = kt & 1;
    const int gcur = (kt + phase) & 31;

    const f16* vt = vgp + ((size_t)gcur << 13);
    const f16x8 av0 = *(const f16x8*)(vt);
    const f16x8 av1 = *(const f16x8*)(vt + 128);
    const f16x8 av2 = *(const f16x8*)(vt + 256);
    const f16x8 av3 = *(const f16x8*)(vt + 384);

    {
      const int tn = (kt + 1 + phase) & 31;
      f16* kd = kbuf[cur ^ 1] + (wv << 10);
      dma16(kg0 + ((size_t)tn << 10),       kd);
      dma16(kg0 + ((size_t)tn << 10) + 512, kd + 512);
    }

    const f16* kc = kbuf[cur];
    const f16x8 ak00 = *(const f16x8*)(kc + (quad << 10) + koff0);
    const f16x8 ak01 = *(const f16x8*)(kc + ((4 + quad) << 10) + koff0);
    const f16x8 ak10 = *(const f16x8*)(kc + (quad << 10) + koff1);
    const f16x8 ak11 = *(const f16x8*)(kc + ((4 + quad) << 10) + koff1);

    f32x4 z0, z1;
    {
      f32x4 z = {0.f, 0.f, 0.f, 0.f};
      z = __builtin_amdgcn_mfma_f32_16x16x32_f16(ak00, bq0, z, 0, 0, 0);
      z0 = __builtin_amdgcn_mfma_f32_16x16x32_f16(ak01, bq1, z, 0, 0, 0);
    }
    {
      f32x4 z = {0.f, 0.f, 0.f, 0.f};
      z = __builtin_amdgcn_mfma_f32_16x16x32_f16(ak10, bq0, z, 0, 0, 0);
      z1 = __builtin_amdgcn_mfma_f32_16x16x32_f16(ak11, bq1, z, 0, 0, 0);
    }

    float tmax = fmaxf(fmaxf(fmaxf(z0[0], z0[1]), fmaxf(z0[2], z0[3])),
                       fmaxf(fmaxf(z1[0], z1[1]), fmaxf(z1[2], z1[3])));
    tmax = fmaxf(tmax, __shfl_xor(tmax, 16, 64));
    tmax = fmaxf(tmax, __shfl_xor(tmax, 32, 64));
    const bool need = !__all(tmax <= m + 8.f);    // defer-max, THR=8
    const float mn = need ? fmaxf(m, tmax) : m;

    const float p0 = fexp2(z0[0] - mn);
    const float p1 = fexp2(z0[1] - mn);
    const float p2 = fexp2(z0[2] - mn);
    const float p3 = fexp2(z0[3] - mn);
    const float p4 = fexp2(z1[0] - mn);
    const float p5 = fexp2(z1[1] - mn);
    const float p6 = fexp2(z1[2] - mn);
    const float p7 = fexp2(z1[3] - mn);
    const float ts = ((p0 + p1) + (p2 + p3)) + ((p4 + p5) + (p6 + p7));

    f16x8 pa;   // P^T B-frag: k-order == reg order (by K permutation)
    pa[0] = f2h(p0); pa[1] = f2h(p1); pa[2] = f2h(p2); pa[3] = f2h(p3);
    pa[4] = f2h(p4); pa[5] = f2h(p5); pa[6] = f2h(p6); pa[7] = f2h(p7);

    if (need) {
      const float al = fexp2(m - mn);   // lane-local (q in column)
      lp = lp * al + ts;
      m = mn;
#pragma unroll
      for (int ct = 0; ct < 4; ++ct)
        for (int r = 0; r < 4; ++r) o[ct][r] *= al;
    } else {
      lp += ts;
    }

    o[0] = __builtin_amdgcn_mfma_f32_16x16x32_f16(av0, pa, o[0], 0, 0, 0);
    o[1] = __builtin_amdgcn_mfma_f32_16x16x32_f16(av1, pa, o[1], 0, 0, 0);
    o[2] = __builtin_amdgcn_mfma_f32_16x16x32_f16(av2, pa, o[2], 0, 0, 0);
    o[3] = __builtin_amdgcn_mfma_f32_16x16x32_f16(av3, pa, o[3], 0, 0, 0);
    __syncthreads();   // K DMA landed + all waves done with kbuf
  }

  {
    float v = lp;
    v += __shfl_xor(v, 16, 64);
    v += __shfl_xor(v, 32, 64);
    if (quad == 0) {
      ldsM[ks][qh * 16 + l15] = m;
      ldsL[ks][qh * 16 + l15] = v;
    }
  }
  __syncthreads();

  if (tid < 32) {
    const float M = fmaxf(fmaxf(ldsM[0][tid], ldsM[1][tid]),
                          fmaxf(ldsM[2][tid], ldsM[3][tid]));
    const float lt = ldsL[0][tid] * fexp2(ldsM[0][tid] - M) +
                     ldsL[1][tid] * fexp2(ldsM[1][tid] - M) +
                     ldsL[2][tid] * fexp2(ldsM[2][tid] - M) +
                     ldsL[3][tid] * fexp2(ldsM[3][tid] - M);
    ldsMg[tid] = M;
    ldsInv[tid] = 1.f / lt;
  }
  __syncthreads();

  {
    const int q = qh * 16 + l15;
    const float sc = fexp2(m - ldsMg[q]);
#pragma unroll
    for (int ct = 0; ct < 4; ++ct)
      for (int r = 0; r < 4; ++r)
        atomicAdd(&ldsO[q * 65 + ct * 16 + quad * 4 + r], o[ct][r] * sc);
  }
  __syncthreads();

  // BN partial sums (val recomputed in phase C from ldsO; no y0 store)
  const float g = gam[0];
  {
    const int c = tid >> 3;              // 0..63
    const int q0 = (tid & 7) << 2;       // 0..28
    float s1 = 0.f, s2 = 0.f;
#pragma unroll
    for (int r = 0; r < 4; ++r) {
      const float val = g * ldsO[(q0 + r) * 65 + c] * ldsInv[q0 + r];
      s1 += val; s2 += val * val;
    }
    s1 += __shfl_xor(s1, 1, 64);
    s2 += __shfl_xor(s2, 1, 64);
    s1 += __shfl_xor(s1, 2, 64);
    s2 += __shfl_xor(s2, 2, 64);
    s1 += __shfl_xor(s1, 4, 64);
    s2 += __shfl_xor(s2, 4, 64);
    if ((tid & 7) == 0) {
      atomicAdd(&gs1[c], s1);
      atomicAdd(&gs2[c], s2);
    }
  }

  // ===== grid barrier 2: BN stats complete =====
  __syncthreads();
  __threadfence();
  if (tid == 0) {
    atomicAdd(ctr + 1, 1);
    while (__hip_atomic_load(ctr + 1, __ATOMIC_RELAXED, __HIP_MEMORY_SCOPE_AGENT) < 512)
      __builtin_amdgcn_s_sleep(8);
  }
  __syncthreads();
  __threadfence();

  // ===== Phase C: BN + residual straight from LDS =====
  {
    const int c = tid >> 3;              // 0..63
    const int q0 = (tid & 7) << 2;       // 0..28
    const float inv_n = 1.f / 16384.f;
    const float mean = gs1[c] * inv_n;
    const float var = fmaxf(gs2[c] * inv_n - mean * mean, 0.f);
    const float bsc = bnw[c] * rsqrtf(var + 1e-5f);
    const float bsh = bnb[c] - mean * bsc;
    const size_t base = ((size_t)(b * 64 + c) << 12) + qb0 + q0;
    const float4 xv = *(const float4*)(x + base);
    const float* xp = &xv.x;
    float4 ov;
    float* op = &ov.x;
#pragma unroll
    for (int r = 0; r < 4; ++r) {
      const float val = g * ldsO[(q0 + r) * 65 + c] * ldsInv[q0 + r];
      op[r] = val * bsc + bsh + xp[r];
    }
    *(float4*)(out + base) = ov;
  }
}

// ---------------------------------------------------------------------------
extern "C" void kernel_launch(void* const* d_in, const int* in_sizes, int n_in,
                              void* d_out, int out_size, void* d_ws, size_t ws_size,
                              hipStream_t stream)
{
  (void)in_sizes; (void)n_in; (void)out_size; (void)ws_size;
  const float* x   = (const float*)d_in[0];
  const float* qw  = (const float*)d_in[1];
  const float* kw  = (const float*)d_in[2];
  const float* vw  = (const float*)d_in[3];
  const float* vb  = (const float*)d_in[4];
  const float* gam = (const float*)d_in[5];
  const float* bnw = (const float*)d_in[6];
  const float* bnb = (const float*)d_in[7];

  char* ws = (char*)d_ws;
  f16*   qa  = (f16*)(ws);
  f16*   ka2 = (f16*)(ws + (2u << 20));
  f16*   va3 = (f16*)(ws + (4u << 20));
  float* gs1 = (float*)(ws + (6u << 20));           // 64 floats
  float* gs2 = (float*)(ws + (6u << 20) + 256);     // 64 floats
  int*   ctr = (int*)(ws + (6u << 20) + 512);       // 2 ints

  pam_zero <<<1, 256, 0, stream>>>(gs1, ctr);
  pam_fused<<<512, 512, 0, stream>>>(x, qw, kw, vw, vb, gam, bnw, bnb,
                                     qa, ka2, va3, gs1, gs2, ctr, (float*)d_out);
}

// Round 9
// 165.930 us; speedup vs baseline: 2.4859x; 2.4859x over previous
//
#include <hip/hip_runtime.h>
#include <stdint.h>

using f16 = _Float16;

typedef _Float16 f16x8 __attribute__((ext_vector_type(8)));
typedef _Float16 f16x4 __attribute__((ext_vector_type(4)));
typedef float f32x4 __attribute__((ext_vector_type(4)));

#define LOG2E 1.44269504088896340736f

__device__ __forceinline__ f16 f2h(float f) { return (f16)f; }  // RNE

#if __has_builtin(__builtin_amdgcn_exp2f)
__device__ __forceinline__ float fexp2(float x) { return __builtin_amdgcn_exp2f(x); }
#else
__device__ __forceinline__ float fexp2(float x) { return exp2f(x); }
#endif

typedef __attribute__((address_space(1))) const uint32_t gu32;
typedef __attribute__((address_space(3))) uint32_t lu32;

__device__ __forceinline__ void dma16(const void* g, void* l) {
  // global->LDS DMA, 16 B/lane. Global source is PER-LANE (caller includes
  // lane*16B); LDS dest is wave-uniform base + lane*16 auto-stride.
  __builtin_amdgcn_global_load_lds((gu32*)g, (lu32*)l, 16, 0, 0);
}

__device__ __forceinline__ f16x8 cvt8(const float* p) {
  const float4 a = *(const float4*)p;
  const float4 b = *(const float4*)(p + 4);
  f16x8 r;
  r[0] = (f16)a.x; r[1] = (f16)a.y; r[2] = (f16)a.z; r[3] = (f16)a.w;
  r[4] = (f16)b.x; r[5] = (f16)b.y; r[6] = (f16)b.z; r[7] = (f16)b.w;
  return r;
}

// B=4, C=64, N=4096.  Global in/out FP32; internal tensor-core path FP16.
// ws layout (bytes):
//   0     qa  f16 [4][4096][64]      (2 MB)  q*log2e, position-major
//   2 MB  ka2 f16 [4][8][4096][8]    (2 MB)  K: [b][c8][key'][8c], key' = key
//                                            ^ ((key>>3&1)<<2 | (key>>4&1))
//   4 MB  va3 f16 [4][512][64][8]    (2 MB)  V key-chunked: [b][k8][c][8k]
//   6 MB  gs1[64] | gs2[64] | ctr[2] (BN stats + barrier ticket; zeroed by
//                                     pre block 0 each launch/replay)
// y0 is GONE: BN+residual applied straight from LDS in the fused kernel.

// ---------------------------------------------------------------------------
// pre v3 (r7 verbatim + ctr zeroing): 1024 blocks x 256 thr, 16-pos tiles.
// ---------------------------------------------------------------------------
__global__ __launch_bounds__(256, 2) void pam_pre(
    const float* __restrict__ x, const float* __restrict__ qw,
    const float* __restrict__ kw, const float* __restrict__ vw,
    const float* __restrict__ vb,
    f16* __restrict__ qa, f16* __restrict__ ka2, f16* __restrict__ va3,
    float* __restrict__ gz)
{
  __shared__ alignas(16) f16 xt[16 * 72];   // xt[n][c] f16, row stride 72
  const int tid = threadIdx.x;
  const int b = blockIdx.x >> 8;
  const int n0 = (blockIdx.x & 255) << 4;
  const int lane = tid & 63;
  const int wv = tid >> 6;
  const int quad = lane >> 4, l15 = lane & 15;

  // gs1|gs2|ctr zero-init (132 words covers 128 stats + 2 ints + pad)
  if (blockIdx.x == 0 && tid < 132) gz[tid] = 0.f;

  // stage x[b][c][n0:+16] (fp32) transposed into xt[n][c] (f16)
  {
    const int c = tid >> 2;
    const int j0 = (tid & 3) << 2;
    const float4 v0 = *(const float4*)(x + ((size_t)(b * 64 + c) << 12) + n0 + j0);
    xt[(j0 + 0) * 72 + c] = f2h(v0.x);
    xt[(j0 + 1) * 72 + c] = f2h(v0.y);
    xt[(j0 + 2) * 72 + c] = f2h(v0.z);
    xt[(j0 + 3) * 72 + c] = f2h(v0.w);
  }
  __syncthreads();

  // conv over channel axis (SAME, zero pad): 128 threads, 8 channels each
  if (tid < 128) {
    const float qw0 = qw[0], qw1 = qw[1], qw2 = qw[2];
    const float kw0 = kw[0], kw1 = kw[1], kw2 = kw[2];
    const int n = tid >> 3;            // 0..15
    const int c8 = tid & 7;            // 0..7
    const f16x8 v0 = *(const f16x8*)&xt[n * 72 + c8 * 8];
    const float lm = (c8 > 0) ? (float)xt[n * 72 + c8 * 8 - 1] : 0.f;
    const float rp = (c8 < 7) ? (float)xt[n * 72 + c8 * 8 + 8] : 0.f;
    f16x8 qv8, kv8;
#pragma unroll
    for (int j = 0; j < 8; ++j) {
      const float xm = (j == 0) ? lm : (float)v0[j - 1];
      const float x0 = (float)v0[j];
      const float xp = (j == 7) ? rp : (float)v0[j + 1];
      qv8[j] = f2h((qw0 * xm + qw1 * x0 + qw2 * xp) * LOG2E);  // log2-domain
      kv8[j] = f2h(kw0 * xm + kw1 * x0 + kw2 * xp);
    }
    const int nn = n0 + n;
    *(f16x8*)(qa + ((size_t)((b << 12) + nn) << 6) + c8 * 8) = qv8;
    // bank-fix storage permutation: flip key bits [2],[0] by bits [3],[4]
    const int np = nn ^ ((((nn >> 3) & 1) << 2) | ((nn >> 4) & 1));
    *(f16x8*)(ka2 + (((size_t)(b * 8 + c8)) << 15) + (np << 3)) = kv8;
  }

  // v^T[n][co] via mfma; wave wv -> co columns [16wv,+16)
  {
    const f16x8 a0 = *(const f16x8*)&xt[l15 * 72 + quad * 8];
    const f16x8 a1 = *(const f16x8*)&xt[l15 * 72 + quad * 8 + 32];
    const int co = wv * 16 + l15;
    const f16x8 b0 = cvt8(vw + co * 64 + quad * 8);
    const f16x8 b1 = cvt8(vw + co * 64 + quad * 8 + 32);
    f32x4 z = {0.f, 0.f, 0.f, 0.f};
    z = __builtin_amdgcn_mfma_f32_16x16x32_f16(a0, b0, z, 0, 0, 0);
    z = __builtin_amdgcn_mfma_f32_16x16x32_f16(a1, b1, z, 0, 0, 0);
    const float vbv = vb[co];
    f16x4 pv;
#pragma unroll
    for (int r = 0; r < 4; ++r) pv[r] = f2h(z[r] + vbv);
    const int nb = n0 + quad * 4;      // 4 consecutive n per thread
    *(f16x4*)(va3 + (((size_t)(b * 512 + (nb >> 3))) << 9)
              + (co << 3) + (nb & 7)) = pv;
  }
}

// ---------------------------------------------------------------------------
// attention v23 = r7 attn (the measured best: 512 thr, K 128-key DMA double-
// buffer, V global->VGPR, XOR K-perm gather, O^T PV, defer-max) FUSED with
// the BN+residual apply via a FENCE-FREE grid barrier:
//  - only cross-block data after attn is gs1/gs2, communicated entirely via
//    device-scope atomics (atomicAdd write, agent-scope atomic-load read) --
//    coherent at the coherence point WITHOUT any __threadfence, so no L2
//    writeback/invalidate storm (r8's failure mode).
//  - ordering: __syncthreads() before the ticket drains each wave's vmcnt
//    (all gs atomicAdds performed); ticket = release atomicAdd; spin relaxed.
//  - phase C applies BN straight from ldsO/ldsInv still live in LDS; the
//    12 MB y0 global round-trip is gone, as is one kernel launch (~22 us).
//  - co-residency (deadlock-free spin): 512 blocks, ~43 KB LDS, ~40 VGPR
//    -> >=2 blocks/CU -> capacity >= 512.
// ---------------------------------------------------------------------------
__global__ __launch_bounds__(512, 6) void pam_attn(
    const f16* __restrict__ qa, const f16* __restrict__ ka2,
    const f16* __restrict__ va3, const float* __restrict__ gam,
    const float* __restrict__ x, const float* __restrict__ bnw,
    const float* __restrict__ bnb,
    float* __restrict__ gs1, float* __restrict__ gs2, int* __restrict__ ctr,
    float* __restrict__ out)
{
  __shared__ alignas(16) f16 kbuf[2][8192];   // [c8][128key'][8c], 16 KB each
  __shared__ float ldsO[32 * 65];             // [q][c], pad 65
  __shared__ float ldsM[4][32], ldsL[4][32], ldsMg[32], ldsInv[32];
  __shared__ float ldsStats[128];             // gs1|gs2 snapshot post-barrier

  const int tid = threadIdx.x;
  const int wv = tid >> 6, lane = tid & 63;
  const int quad = lane >> 4, l15 = lane & 15;
  const int ks = wv & 3, qh = wv >> 2;
  const int b = blockIdx.x & 3;
  const int qb = blockIdx.x >> 2;          // 0..127
  const int qb0 = qb << 5;
  const int phase = qb & 31;               // anti-convoy rotation (32 tiles)

  for (int i = tid; i < 32 * 65; i += 512) ldsO[i] = 0.f;

  const int bn = b << 12;
  // Q fragments (B-operand: col=l15=q, k=quad*8+j over channels)
  f16x8 bq0, bq1;
  {
    const int q = qb0 + qh * 16 + l15;
    const f16* qp = qa + ((size_t)(bn + q) << 6) + quad * 8;
    bq0 = *(const f16x8*)qp;
    bq1 = *(const f16x8*)(qp + 32);
  }

  // K staging base (PER-LANE source: + lane*8 f16 = 16 B/lane).
  const f16* kg0 = ka2 + (((size_t)(b * 8 + wv)) << 15) + (lane << 3);
  // V per-lane global base: va3[b][k8 = 16*g + ks*4 + quad][c][8k], +l15*8
  const f16* vgp = va3 + ((size_t)b << 18) + ((ks * 4 + quad) << 9) + (l15 << 3);

  f32x4 o[4] = {};                 // O^T: col=l15=q, row c = ct*16+quad*4+r
  float m = -1e30f, lp = 0.f;

  // stage K tile 'phase' into buf 0
  dma16(kg0 + ((size_t)phase << 10),       kbuf[0] + (wv << 10));
  dma16(kg0 + ((size_t)phase << 10) + 512, kbuf[0] + (wv << 10) + 512);
  __syncthreads();

  // K gather with both-sides XOR: S^T reg r of quad holds key
  // ks*32 + quad*8 + t*4 + r == PV k-order (zero-shuffle P).
  const int u = l15 >> 2;
  const int xmsk = ((u & 1) << 2) | (u >> 1);
  const int pos0 = (ks << 5) + (u << 3) + (l15 & 3);
  const int koff0 = (pos0 ^ xmsk) << 3;
  const int koff1 = koff0 ^ 32;                // (pos0+4)^mask, same mask

#pragma unroll 1
  for (int kt = 0; kt < 32; ++kt) {
    const int cur = kt & 1;
    const int gcur = (kt + phase) & 31;

    // V fragments for THIS tile: global loads issued first, used at PV
    const f16* vt = vgp + ((size_t)gcur << 13);
    const f16x8 av0 = *(const f16x8*)(vt);
    const f16x8 av1 = *(const f16x8*)(vt + 128);
    const f16x8 av2 = *(const f16x8*)(vt + 256);
    const f16x8 av3 = *(const f16x8*)(vt + 384);

    // prefetch K tile kt+1
    {
      const int tn = (kt + 1 + phase) & 31;
      f16* kd = kbuf[cur ^ 1] + (wv << 10);
      dma16(kg0 + ((size_t)tn << 10),       kd);
      dma16(kg0 + ((size_t)tn << 10) + 512, kd + 512);
    }

    const f16* kc = kbuf[cur];
    const f16x8 ak00 = *(const f16x8*)(kc + (quad << 10) + koff0);
    const f16x8 ak01 = *(const f16x8*)(kc + ((4 + quad) << 10) + koff0);
    const f16x8 ak10 = *(const f16x8*)(kc + (quad << 10) + koff1);
    const f16x8 ak11 = *(const f16x8*)(kc + ((4 + quad) << 10) + koff1);

    // S^T[32 key (permuted)][16 q], contraction over 64 channels
    f32x4 z0, z1;
    {
      f32x4 z = {0.f, 0.f, 0.f, 0.f};
      z = __builtin_amdgcn_mfma_f32_16x16x32_f16(ak00, bq0, z, 0, 0, 0);
      z0 = __builtin_amdgcn_mfma_f32_16x16x32_f16(ak01, bq1, z, 0, 0, 0);
    }
    {
      f32x4 z = {0.f, 0.f, 0.f, 0.f};
      z = __builtin_amdgcn_mfma_f32_16x16x32_f16(ak10, bq0, z, 0, 0, 0);
      z1 = __builtin_amdgcn_mfma_f32_16x16x32_f16(ak11, bq1, z, 0, 0, 0);
    }

    // online softmax: lane holds keys quad*8+{0..7} for query q=l15
    float tmax = fmaxf(fmaxf(fmaxf(z0[0], z0[1]), fmaxf(z0[2], z0[3])),
                       fmaxf(fmaxf(z1[0], z1[1]), fmaxf(z1[2], z1[3])));
    tmax = fmaxf(tmax, __shfl_xor(tmax, 16, 64));
    tmax = fmaxf(tmax, __shfl_xor(tmax, 32, 64));
    const bool need = !__all(tmax <= m + 8.f);    // defer-max, THR=8
    const float mn = need ? fmaxf(m, tmax) : m;

    const float p0 = fexp2(z0[0] - mn);
    const float p1 = fexp2(z0[1] - mn);
    const float p2 = fexp2(z0[2] - mn);
    const float p3 = fexp2(z0[3] - mn);
    const float p4 = fexp2(z1[0] - mn);
    const float p5 = fexp2(z1[1] - mn);
    const float p6 = fexp2(z1[2] - mn);
    const float p7 = fexp2(z1[3] - mn);
    const float ts = ((p0 + p1) + (p2 + p3)) + ((p4 + p5) + (p6 + p7));

    f16x8 pa;   // P^T B-frag: k-order == reg order (by K permutation)
    pa[0] = f2h(p0); pa[1] = f2h(p1); pa[2] = f2h(p2); pa[3] = f2h(p3);
    pa[4] = f2h(p4); pa[5] = f2h(p5); pa[6] = f2h(p6); pa[7] = f2h(p7);

    if (need) {
      const float al = fexp2(m - mn);   // lane-local (q in column)
      lp = lp * al + ts;
      m = mn;
#pragma unroll
      for (int ct = 0; ct < 4; ++ct)
        for (int r = 0; r < 4; ++r) o[ct][r] *= al;
    } else {
      lp += ts;
    }

    // O^T += V * P^T : one K=32 MFMA per 16-channel tile (V from registers)
    o[0] = __builtin_amdgcn_mfma_f32_16x16x32_f16(av0, pa, o[0], 0, 0, 0);
    o[1] = __builtin_amdgcn_mfma_f32_16x16x32_f16(av1, pa, o[1], 0, 0, 0);
    o[2] = __builtin_amdgcn_mfma_f32_16x16x32_f16(av2, pa, o[2], 0, 0, 0);
    o[3] = __builtin_amdgcn_mfma_f32_16x16x32_f16(av3, pa, o[3], 0, 0, 0);
    __syncthreads();   // K DMA landed + all waves done with kbuf
  }

  // publish per-wave online state (m quad-uniform; lp reduced across quads)
  {
    float v = lp;
    v += __shfl_xor(v, 16, 64);
    v += __shfl_xor(v, 32, 64);
    if (quad == 0) {
      ldsM[ks][qh * 16 + l15] = m;
      ldsL[ks][qh * 16 + l15] = v;
    }
  }
  __syncthreads();

  // per-query global max + denom (4 key-slices)
  if (tid < 32) {
    const float M = fmaxf(fmaxf(ldsM[0][tid], ldsM[1][tid]),
                          fmaxf(ldsM[2][tid], ldsM[3][tid]));
    const float lt = ldsL[0][tid] * fexp2(ldsM[0][tid] - M) +
                     ldsL[1][tid] * fexp2(ldsM[1][tid] - M) +
                     ldsL[2][tid] * fexp2(ldsM[2][tid] - M) +
                     ldsL[3][tid] * fexp2(ldsM[3][tid] - M);
    ldsMg[tid] = M;
    ldsInv[tid] = 1.f / lt;
  }
  __syncthreads();

  // m-aware merge of partial O^T across the 4 key-split waves (sc lane-local)
  {
    const int q = qh * 16 + l15;
    const float sc = fexp2(m - ldsMg[q]);
#pragma unroll
    for (int ct = 0; ct < 4; ++ct)
      for (int r = 0; r < 4; ++r)
        atomicAdd(&ldsO[q * 65 + ct * 16 + quad * 4 + r], o[ct][r] * sc);
  }
  __syncthreads();

  // BN partial sums -> device-scope atomics (the ONLY cross-block data)
  const float g = gam[0];
  {
    const int c = tid >> 3;              // 0..63
    const int q0 = (tid & 7) << 2;       // 0..28
    float s1 = 0.f, s2 = 0.f;
#pragma unroll
    for (int r = 0; r < 4; ++r) {
      const float val = g * ldsO[(q0 + r) * 65 + c] * ldsInv[q0 + r];
      s1 += val; s2 += val * val;
    }
    s1 += __shfl_xor(s1, 1, 64);
    s2 += __shfl_xor(s2, 1, 64);
    s1 += __shfl_xor(s1, 2, 64);
    s2 += __shfl_xor(s2, 2, 64);
    s1 += __shfl_xor(s1, 4, 64);
    s2 += __shfl_xor(s2, 4, 64);
    if ((tid & 7) == 0) {
      atomicAdd(&gs1[c], s1);
      atomicAdd(&gs2[c], s2);
    }
  }

  // ===== fence-free grid barrier: gs adds performed -> ticket -> spin =====
  __syncthreads();                 // drains vmcnt: this block's adds performed
  if (tid == 0) {
    __hip_atomic_fetch_add(ctr, 1, __ATOMIC_RELEASE, __HIP_MEMORY_SCOPE_AGENT);
    while (__hip_atomic_load(ctr, __ATOMIC_RELAXED, __HIP_MEMORY_SCOPE_AGENT) < 512)
      __builtin_amdgcn_s_sleep(2);
  }
  __syncthreads();

  // snapshot BN stats via agent-scope atomic loads (bypass stale L1/L2)
  if (tid < 128) {
    const float* src = (tid < 64) ? &gs1[tid] : &gs2[tid - 64];
    ldsStats[tid] = __hip_atomic_load(src, __ATOMIC_RELAXED,
                                      __HIP_MEMORY_SCOPE_AGENT);
  }
  __syncthreads();

  // ===== apply: BN + residual straight from LDS =====
  {
    const int c = tid >> 3;              // 0..63
    const int q0 = (tid & 7) << 2;       // 0..28
    const float inv_n = 1.f / 16384.f;
    const float mean = ldsStats[c] * inv_n;
    const float var = fmaxf(ldsStats[64 + c] * inv_n - mean * mean, 0.f);
    const float bsc = bnw[c] * rsqrtf(var + 1e-5f);
    const float bsh = bnb[c] - mean * bsc;
    const size_t base = ((size_t)(b * 64 + c) << 12) + qb0 + q0;
    const float4 xv = *(const float4*)(x + base);
    const float* xp = &xv.x;
    float4 ov;
    float* op = &ov.x;
#pragma unroll
    for (int r = 0; r < 4; ++r) {
      const float val = g * ldsO[(q0 + r) * 65 + c] * ldsInv[q0 + r];
      op[r] = val * bsc + bsh + xp[r];
    }
    *(float4*)(out + base) = ov;
  }
}

// ---------------------------------------------------------------------------
extern "C" void kernel_launch(void* const* d_in, const int* in_sizes, int n_in,
                              void* d_out, int out_size, void* d_ws, size_t ws_size,
                              hipStream_t stream)
{
  (void)in_sizes; (void)n_in; (void)out_size; (void)ws_size;
  const float* x   = (const float*)d_in[0];
  const float* qw  = (const float*)d_in[1];
  const float* kw  = (const float*)d_in[2];
  const float* vw  = (const float*)d_in[3];
  const float* vb  = (const float*)d_in[4];
  const float* gam = (const float*)d_in[5];
  const float* bnw = (const float*)d_in[6];
  const float* bnb = (const float*)d_in[7];

  char* ws = (char*)d_ws;
  f16*   qa  = (f16*)(ws);
  f16*   ka2 = (f16*)(ws + (2u << 20));
  f16*   va3 = (f16*)(ws + (4u << 20));
  float* gs1 = (float*)(ws + (6u << 20));           // 64 floats
  float* gs2 = (float*)(ws + (6u << 20) + 256);     // 64 floats
  int*   ctr = (int*)(ws + (6u << 20) + 512);       // barrier ticket

  pam_pre  <<<1024, 256, 0, stream>>>(x, qw, kw, vw, vb, qa, ka2, va3, gs1);
  pam_attn <<<512, 512, 0, stream>>>(qa, ka2, va3, gam, x, bnw, bnb,
                                     gs1, gs2, ctr, (float*)d_out);
}

// Round 10
// 148.199 us; speedup vs baseline: 2.7834x; 1.1196x over previous
//
#include <hip/hip_runtime.h>
#include <stdint.h>

using f16 = _Float16;

typedef _Float16 f16x8 __attribute__((ext_vector_type(8)));
typedef _Float16 f16x4 __attribute__((ext_vector_type(4)));
typedef float f32x4 __attribute__((ext_vector_type(4)));

#define LOG2E 1.44269504088896340736f

__device__ __forceinline__ f16 f2h(float f) { return (f16)f; }  // RNE

#if __has_builtin(__builtin_amdgcn_exp2f)
__device__ __forceinline__ float fexp2(float x) { return __builtin_amdgcn_exp2f(x); }
#else
__device__ __forceinline__ float fexp2(float x) { return exp2f(x); }
#endif

typedef __attribute__((address_space(1))) const uint32_t gu32;
typedef __attribute__((address_space(3))) uint32_t lu32;

__device__ __forceinline__ void dma16(const void* g, void* l) {
  // global->LDS DMA, 16 B/lane. Global source is PER-LANE (caller includes
  // lane*16B); LDS dest is wave-uniform base + lane*16 auto-stride.
  __builtin_amdgcn_global_load_lds((gu32*)g, (lu32*)l, 16, 0, 0);
}

__device__ __forceinline__ f16x8 cvt8(const float* p) {
  const float4 a = *(const float4*)p;
  const float4 b = *(const float4*)(p + 4);
  f16x8 r;
  r[0] = (f16)a.x; r[1] = (f16)a.y; r[2] = (f16)a.z; r[3] = (f16)a.w;
  r[4] = (f16)b.x; r[5] = (f16)b.y; r[6] = (f16)b.z; r[7] = (f16)b.w;
  return r;
}

// B=4, C=64, N=4096.  Global in/out FP32; internal tensor-core path FP16.
// ws layout (bytes):
//   0     qa  f16 [4][4096][64]      (2 MB)  q*log2e, position-major
//   2 MB  ka2 f16 [4][8][4096][8]    (2 MB)  K: [b][c8][key'][8c], key' = key
//                                            ^ ((key>>3&1)<<2 | (key>>4&1))
//   4 MB  va3 f16 [4][512][64][8]    (2 MB)  V key-chunked: [b][k8][c][8k]
//   6 MB  y0  f32 [4][64][4096]      (4 MB)  gamma*attn_out, pre-BN
//   10 MB stats: gs1[64] | gs2[64]   (zeroed by pre block 0)

// ---------------------------------------------------------------------------
// pre v3 (r7 verbatim): 1024 blocks x 256 thr, 16-pos tiles, vectorized I/O.
// ---------------------------------------------------------------------------
__global__ __launch_bounds__(256, 2) void pam_pre(
    const float* __restrict__ x, const float* __restrict__ qw,
    const float* __restrict__ kw, const float* __restrict__ vw,
    const float* __restrict__ vb,
    f16* __restrict__ qa, f16* __restrict__ ka2, f16* __restrict__ va3,
    float* __restrict__ gz)
{
  __shared__ alignas(16) f16 xt[16 * 72];   // xt[n][c] f16, row stride 72
  const int tid = threadIdx.x;
  const int b = blockIdx.x >> 8;
  const int n0 = (blockIdx.x & 255) << 4;
  const int lane = tid & 63;
  const int wv = tid >> 6;
  const int quad = lane >> 4, l15 = lane & 15;

  if (blockIdx.x == 0 && tid < 128) gz[tid] = 0.f;   // gs1|gs2 zero-init

  // stage x[b][c][n0:+16] (fp32) transposed into xt[n][c] (f16)
  {
    const int c = tid >> 2;
    const int j0 = (tid & 3) << 2;
    const float4 v0 = *(const float4*)(x + ((size_t)(b * 64 + c) << 12) + n0 + j0);
    xt[(j0 + 0) * 72 + c] = f2h(v0.x);
    xt[(j0 + 1) * 72 + c] = f2h(v0.y);
    xt[(j0 + 2) * 72 + c] = f2h(v0.z);
    xt[(j0 + 3) * 72 + c] = f2h(v0.w);
  }
  __syncthreads();

  // conv over channel axis (SAME, zero pad): 128 threads, 8 channels each
  if (tid < 128) {
    const float qw0 = qw[0], qw1 = qw[1], qw2 = qw[2];
    const float kw0 = kw[0], kw1 = kw[1], kw2 = kw[2];
    const int n = tid >> 3;            // 0..15
    const int c8 = tid & 7;            // 0..7
    const f16x8 v0 = *(const f16x8*)&xt[n * 72 + c8 * 8];
    const float lm = (c8 > 0) ? (float)xt[n * 72 + c8 * 8 - 1] : 0.f;
    const float rp = (c8 < 7) ? (float)xt[n * 72 + c8 * 8 + 8] : 0.f;
    f16x8 qv8, kv8;
#pragma unroll
    for (int j = 0; j < 8; ++j) {
      const float xm = (j == 0) ? lm : (float)v0[j - 1];
      const float x0 = (float)v0[j];
      const float xp = (j == 7) ? rp : (float)v0[j + 1];
      qv8[j] = f2h((qw0 * xm + qw1 * x0 + qw2 * xp) * LOG2E);  // log2-domain
      kv8[j] = f2h(kw0 * xm + kw1 * x0 + kw2 * xp);
    }
    const int nn = n0 + n;
    *(f16x8*)(qa + ((size_t)((b << 12) + nn) << 6) + c8 * 8) = qv8;
    // bank-fix storage permutation: flip key bits [2],[0] by bits [3],[4]
    const int np = nn ^ ((((nn >> 3) & 1) << 2) | ((nn >> 4) & 1));
    *(f16x8*)(ka2 + (((size_t)(b * 8 + c8)) << 15) + (np << 3)) = kv8;
  }

  // v^T[n][co] via mfma; wave wv -> co columns [16wv,+16)
  {
    const f16x8 a0 = *(const f16x8*)&xt[l15 * 72 + quad * 8];
    const f16x8 a1 = *(const f16x8*)&xt[l15 * 72 + quad * 8 + 32];
    const int co = wv * 16 + l15;
    const f16x8 b0 = cvt8(vw + co * 64 + quad * 8);
    const f16x8 b1 = cvt8(vw + co * 64 + quad * 8 + 32);
    f32x4 z = {0.f, 0.f, 0.f, 0.f};
    z = __builtin_amdgcn_mfma_f32_16x16x32_f16(a0, b0, z, 0, 0, 0);
    z = __builtin_amdgcn_mfma_f32_16x16x32_f16(a1, b1, z, 0, 0, 0);
    const float vbv = vb[co];
    f16x4 pv;
#pragma unroll
    for (int r = 0; r < 4; ++r) pv[r] = f2h(z[r] + vbv);
    const int nb = n0 + quad * 4;      // 4 consecutive n per thread
    *(f16x4*)(va3 + (((size_t)(b * 512 + (nb >> 3))) << 9)
              + (co << 3) + (nb & 7)) = pv;
  }
}

// ---------------------------------------------------------------------------
// attention v24 = r7 skeleton (512 thr, 8 waves, 128-key tiles, V in VGPRs,
// XOR K-perm gather -> zero-shuffle P, O^T PV, defer-max, 2 blocks/CU) with
// the ONLY change being the sync mechanism: K quad-buffer + prefetch
// DISTANCE 2 + counted vmcnt (T4).
//  - each iter t: issue V(t) loads, then [sched_barrier] DMA K(t+2); end
//    with `s_waitcnt vmcnt(2)` + raw s_barrier.  DMA(t+2) stays IN FLIGHT
//    across the barrier and gets a full iteration (~2500 cy) to land --
//    r7's per-iteration vmcnt(0) drain of a just-issued DMA is gone.
//  - correctness: V issued BEFORE K-DMA, so the compiler's own wait for V
//    at PV (vmcnt<=2, in-order retirement) retires DMA(t+1): each wave's
//    tile-(t+1) section is landed before it reaches the end barrier.
//    Buffer WAR is 2 barriers apart.  vmcnt(0) once after the loop (LDS
//    dealloc safety).
//  - LDS: 64K kbuf + 8.3K ldsO + 1.3K stats = 73.6 KB -> still 2 blocks/CU.
// ---------------------------------------------------------------------------
__global__ __launch_bounds__(512, 4) void pam_attn(
    const f16* __restrict__ qa, const f16* __restrict__ ka2,
    const f16* __restrict__ va3, const float* __restrict__ gam,
    float* __restrict__ y0, float* __restrict__ gs1, float* __restrict__ gs2)
{
  __shared__ alignas(16) f16 kbuf[4][8192];   // [c8][128key'][8c], 16 KB/slot
  __shared__ float ldsO[32 * 65];             // [q][c], pad 65
  __shared__ float ldsM[4][32], ldsL[4][32], ldsMg[32], ldsInv[32];

  const int tid = threadIdx.x;
  const int wv = tid >> 6, lane = tid & 63;
  const int quad = lane >> 4, l15 = lane & 15;
  const int ks = wv & 3, qh = wv >> 2;
  const int b = blockIdx.x & 3;
  const int qb = blockIdx.x >> 2;          // 0..127
  const int qb0 = qb << 5;
  const int phase = qb & 31;               // anti-convoy rotation (32 tiles)

  for (int i = tid; i < 32 * 65; i += 512) ldsO[i] = 0.f;

  const int bn = b << 12;
  // Q fragments (B-operand: col=l15=q, k=quad*8+j over channels)
  f16x8 bq0, bq1;
  {
    const int q = qb0 + qh * 16 + l15;
    const f16* qp = qa + ((size_t)(bn + q) << 6) + quad * 8;
    bq0 = *(const f16x8*)qp;
    bq1 = *(const f16x8*)(qp + 32);
  }

  // K staging base (PER-LANE source: + lane*8 f16 = 16 B/lane).
  const f16* kg0 = ka2 + (((size_t)(b * 8 + wv)) << 15) + (lane << 3);
  // V per-lane global base: va3[b][k8 = 16*g + ks*4 + quad][c][8k], +l15*8
  const f16* vgp = va3 + ((size_t)b << 18) + ((ks * 4 + quad) << 9) + (l15 << 3);

  f32x4 o[4] = {};                 // O^T: col=l15=q, row c = ct*16+quad*4+r
  float m = -1e30f, lp = 0.f;

  // prologue: stage tiles phase+0 -> slot 0, phase+1 -> slot 1
  {
    const int g0 = phase;
    const int g1 = (1 + phase) & 31;
    dma16(kg0 + ((size_t)g0 << 10),       kbuf[0] + (wv << 10));
    dma16(kg0 + ((size_t)g0 << 10) + 512, kbuf[0] + (wv << 10) + 512);
    dma16(kg0 + ((size_t)g1 << 10),       kbuf[1] + (wv << 10));
    dma16(kg0 + ((size_t)g1 << 10) + 512, kbuf[1] + (wv << 10) + 512);
  }
  asm volatile("s_waitcnt vmcnt(2)" ::: "memory");   // tile 0 landed
  __builtin_amdgcn_s_barrier();

  // K gather with both-sides XOR: S^T reg r of quad holds key
  // ks*32 + quad*8 + t*4 + r == PV k-order (zero-shuffle P).
  const int u = l15 >> 2;
  const int xmsk = ((u & 1) << 2) | (u >> 1);
  const int pos0 = (ks << 5) + (u << 3) + (l15 & 3);
  const int koff0 = (pos0 ^ xmsk) << 3;
  const int koff1 = koff0 ^ 32;                // (pos0+4)^mask, same mask

#pragma unroll 1
  for (int kt = 0; kt < 32; ++kt) {
    const int cur = kt & 3;
    const int gcur = (kt + phase) & 31;

    // V fragments for THIS tile: issued FIRST (so the compiler's V-wait at
    // PV retires the older DMA(t+1) in-order -- the correctness anchor)
    const f16* vt = vgp + ((size_t)gcur << 13);
    const f16x8 av0 = *(const f16x8*)(vt);
    const f16x8 av1 = *(const f16x8*)(vt + 128);
    const f16x8 av2 = *(const f16x8*)(vt + 256);
    const f16x8 av3 = *(const f16x8*)(vt + 384);
    __builtin_amdgcn_sched_barrier(0);   // pin: V issues stay above the DMA

    // prefetch K tile kt+2 (distance 2) into slot (kt+2)&3
    if (kt < 30) {
      const int tn = (kt + 2 + phase) & 31;
      f16* kd = kbuf[(kt + 2) & 3] + (wv << 10);
      dma16(kg0 + ((size_t)tn << 10),       kd);
      dma16(kg0 + ((size_t)tn << 10) + 512, kd + 512);
    }

    const f16* kc = kbuf[cur];
    const f16x8 ak00 = *(const f16x8*)(kc + (quad << 10) + koff0);
    const f16x8 ak01 = *(const f16x8*)(kc + ((4 + quad) << 10) + koff0);
    const f16x8 ak10 = *(const f16x8*)(kc + (quad << 10) + koff1);
    const f16x8 ak11 = *(const f16x8*)(kc + ((4 + quad) << 10) + koff1);

    // S^T[32 key (permuted)][16 q], contraction over 64 channels
    f32x4 z0, z1;
    {
      f32x4 z = {0.f, 0.f, 0.f, 0.f};
      z = __builtin_amdgcn_mfma_f32_16x16x32_f16(ak00, bq0, z, 0, 0, 0);
      z0 = __builtin_amdgcn_mfma_f32_16x16x32_f16(ak01, bq1, z, 0, 0, 0);
    }
    {
      f32x4 z = {0.f, 0.f, 0.f, 0.f};
      z = __builtin_amdgcn_mfma_f32_16x16x32_f16(ak10, bq0, z, 0, 0, 0);
      z1 = __builtin_amdgcn_mfma_f32_16x16x32_f16(ak11, bq1, z, 0, 0, 0);
    }

    // online softmax: lane holds keys quad*8+{0..7} for query q=l15
    float tmax = fmaxf(fmaxf(fmaxf(z0[0], z0[1]), fmaxf(z0[2], z0[3])),
                       fmaxf(fmaxf(z1[0], z1[1]), fmaxf(z1[2], z1[3])));
    tmax = fmaxf(tmax, __shfl_xor(tmax, 16, 64));
    tmax = fmaxf(tmax, __shfl_xor(tmax, 32, 64));
    const bool need = !__all(tmax <= m + 8.f);    // defer-max, THR=8
    const float mn = need ? fmaxf(m, tmax) : m;

    const float p0 = fexp2(z0[0] - mn);
    const float p1 = fexp2(z0[1] - mn);
    const float p2 = fexp2(z0[2] - mn);
    const float p3 = fexp2(z0[3] - mn);
    const float p4 = fexp2(z1[0] - mn);
    const float p5 = fexp2(z1[1] - mn);
    const float p6 = fexp2(z1[2] - mn);
    const float p7 = fexp2(z1[3] - mn);
    const float ts = ((p0 + p1) + (p2 + p3)) + ((p4 + p5) + (p6 + p7));

    f16x8 pa;   // P^T B-frag: k-order == reg order (by K permutation)
    pa[0] = f2h(p0); pa[1] = f2h(p1); pa[2] = f2h(p2); pa[3] = f2h(p3);
    pa[4] = f2h(p4); pa[5] = f2h(p5); pa[6] = f2h(p6); pa[7] = f2h(p7);

    if (need) {
      const float al = fexp2(m - mn);   // lane-local (q in column)
      lp = lp * al + ts;
      m = mn;
#pragma unroll
      for (int ct = 0; ct < 4; ++ct)
        for (int r = 0; r < 4; ++r) o[ct][r] *= al;
    } else {
      lp += ts;
    }

    // O^T += V * P^T : one K=32 MFMA per 16-channel tile (V from registers;
    // the compiler's vmcnt wait here retires DMA(t+1) -- in-order)
    o[0] = __builtin_amdgcn_mfma_f32_16x16x32_f16(av0, pa, o[0], 0, 0, 0);
    o[1] = __builtin_amdgcn_mfma_f32_16x16x32_f16(av1, pa, o[1], 0, 0, 0);
    o[2] = __builtin_amdgcn_mfma_f32_16x16x32_f16(av2, pa, o[2], 0, 0, 0);
    o[3] = __builtin_amdgcn_mfma_f32_16x16x32_f16(av3, pa, o[3], 0, 0, 0);

    // counted sync: DMA(t+1) provably landed (<=2 leaves only DMA(t+2))
    asm volatile("s_waitcnt vmcnt(2)" ::: "memory");
    __builtin_amdgcn_s_barrier();
  }

  // drain trailing DMAs before any LDS reuse / block exit
  asm volatile("s_waitcnt vmcnt(0)" ::: "memory");

  // publish per-wave online state (m quad-uniform; lp reduced across quads)
  {
    float v = lp;
    v += __shfl_xor(v, 16, 64);
    v += __shfl_xor(v, 32, 64);
    if (quad == 0) {
      ldsM[ks][qh * 16 + l15] = m;
      ldsL[ks][qh * 16 + l15] = v;
    }
  }
  __syncthreads();

  // per-query global max + denom (4 key-slices)
  if (tid < 32) {
    const float M = fmaxf(fmaxf(ldsM[0][tid], ldsM[1][tid]),
                          fmaxf(ldsM[2][tid], ldsM[3][tid]));
    const float lt = ldsL[0][tid] * fexp2(ldsM[0][tid] - M) +
                     ldsL[1][tid] * fexp2(ldsM[1][tid] - M) +
                     ldsL[2][tid] * fexp2(ldsM[2][tid] - M) +
                     ldsL[3][tid] * fexp2(ldsM[3][tid] - M);
    ldsMg[tid] = M;
    ldsInv[tid] = 1.f / lt;
  }
  __syncthreads();

  // m-aware merge of partial O^T across the 4 key-split waves (sc lane-local)
  {
    const int q = qh * 16 + l15;
    const float sc = fexp2(m - ldsMg[q]);
#pragma unroll
    for (int ct = 0; ct < 4; ++ct)
      for (int r = 0; r < 4; ++r)
        atomicAdd(&ldsO[q * 65 + ct * 16 + quad * 4 + r], o[ct][r] * sc);
  }
  __syncthreads();

  // epilogue: y0[b][c][n] = gamma * O / l ; BN partial sums
  const float g = gam[0];
  {
    const int c = tid >> 3;              // 0..63
    const int q0 = (tid & 7) << 2;       // 0..28
    float4 v4;
    float* vp = &v4.x;
    float s1 = 0.f, s2 = 0.f;
    for (int r = 0; r < 4; ++r) {
      const float val = g * ldsO[(q0 + r) * 65 + c] * ldsInv[q0 + r];
      vp[r] = val; s1 += val; s2 += val * val;
    }
    *(float4*)(y0 + ((size_t)(b * 64 + c) << 12) + qb0 + q0) = v4;
    s1 += __shfl_xor(s1, 1, 64);
    s2 += __shfl_xor(s2, 1, 64);
    s1 += __shfl_xor(s1, 2, 64);
    s2 += __shfl_xor(s2, 2, 64);
    s1 += __shfl_xor(s1, 4, 64);
    s2 += __shfl_xor(s2, 4, 64);
    if ((tid & 7) == 0) {
      atomicAdd(&gs1[c], s1);
      atomicAdd(&gs2[c], s2);
    }
  }
}

// ---------------------------------------------------------------------------
// apply: BN(scale/shift from gs1/gs2) + residual.
// ---------------------------------------------------------------------------
__global__ __launch_bounds__(256, 2) void pam_apply(
    const float* __restrict__ y0, const float* __restrict__ x,
    const float* __restrict__ gs1, const float* __restrict__ gs2,
    const float* __restrict__ bnw, const float* __restrict__ bnb,
    float* __restrict__ out)
{
  const int i = (blockIdx.x * 256 + threadIdx.x) << 2;   // 4 elems/thread
  const int c = (i >> 12) & 63;
  const float inv_n = 1.f / 16384.f;
  const float mean = gs1[c] * inv_n;
  const float var = fmaxf(gs2[c] * inv_n - mean * mean, 0.f);
  const float sc = bnw[c] * rsqrtf(var + 1e-5f);
  const float sh = bnb[c] - mean * sc;
  const float4 y = *(const float4*)(y0 + i);
  const float4 xv = *(const float4*)(x + i);
  float4 r;
  r.x = y.x * sc + sh + xv.x;
  r.y = y.y * sc + sh + xv.y;
  r.z = y.z * sc + sh + xv.z;
  r.w = y.w * sc + sh + xv.w;
  *(float4*)(out + i) = r;
}

// ---------------------------------------------------------------------------
extern "C" void kernel_launch(void* const* d_in, const int* in_sizes, int n_in,
                              void* d_out, int out_size, void* d_ws, size_t ws_size,
                              hipStream_t stream)
{
  (void)in_sizes; (void)n_in; (void)out_size; (void)ws_size;
  const float* x   = (const float*)d_in[0];
  const float* qw  = (const float*)d_in[1];
  const float* kw  = (const float*)d_in[2];
  const float* vw  = (const float*)d_in[3];
  const float* vb  = (const float*)d_in[4];
  const float* gam = (const float*)d_in[5];
  const float* bnw = (const float*)d_in[6];
  const float* bnb = (const float*)d_in[7];

  char* ws = (char*)d_ws;
  f16*   qa  = (f16*)(ws);
  f16*   ka2 = (f16*)(ws + (2u << 20));
  f16*   va3 = (f16*)(ws + (4u << 20));
  float* y0  = (float*)(ws + (6u << 20));
  float* gs1 = (float*)(ws + (10u << 20));          // 64 floats
  float* gs2 = (float*)(ws + (10u << 20) + 256);    // 64 floats (contiguous)

  pam_pre  <<<1024, 256, 0, stream>>>(x, qw, kw, vw, vb, qa, ka2, va3, gs1);
  pam_attn <<<512, 512, 0, stream>>>(qa, ka2, va3, gam, y0, gs1, gs2);
  pam_apply<<<1024, 256, 0, stream>>>(y0, x, gs1, gs2, bnw, bnb, (float*)d_out);
}